// Round 1
// baseline (670.044 us; speedup 1.0000x reference)
//
#include <hip/hip_runtime.h>
#include <hip/hip_bf16.h>
#include <stdint.h>

#define CDIM 256
#define HH 36
#define WW 36
#define NPX 1296          // 36*36
#define PW 38             // padded width (1-px halo)
#define PPIX 1444         // 38*38
#define NIMG 32
#define NROI 512
#define FCK 4096
#define EPS_BN 1e-5f

typedef __bf16 bf16;
typedef __bf16 bf16x8 __attribute__((ext_vector_type(8)));
typedef float f32x4 __attribute__((ext_vector_type(4)));
typedef unsigned short us8 __attribute__((ext_vector_type(8)));

// async global->LDS, 16B per lane; LDS dest is wave-uniform base + lane*16
#define GLD16(g, l) __builtin_amdgcn_global_load_lds( \
    (__attribute__((address_space(1))) void*)(g),     \
    (__attribute__((address_space(3))) void*)(l), 16, 0, 0)

// ---------------- weight reorder: w[co][ci][kh][kw] f32 -> wb[tap][co][ci] bf16
__global__ void k_wconv(const float* __restrict__ wsrc, bf16* __restrict__ wb) {
  int i = blockIdx.x * 256 + threadIdx.x;
  if (i >= 9 * CDIM * CDIM) return;
  int tap = i / (CDIM * CDIM);
  int rem = i - tap * (CDIM * CDIM);
  int co = rem >> 8, ci = rem & 255;
  wb[i] = (bf16)wsrc[(size_t)(co * CDIM + ci) * 9 + tap];
}

// ---------------- generic f32 -> bf16 cast
__global__ void k_cast(const float* __restrict__ src, bf16* __restrict__ dst, int nElem) {
  int i = blockIdx.x * 256 + threadIdx.x;
  if (i < nElem) dst[i] = (bf16)src[i];
}

// ---------------- feat NCHW f32 -> padded NHWC bf16 (interior only; halo pre-zeroed)
__global__ void k_convert(const float* __restrict__ feat, bf16* __restrict__ xp) {
  int h = blockIdx.x, n = blockIdx.y, c = threadIdx.x;
  const float* src = feat + ((size_t)(n * CDIM + c) * HH + h) * WW;
  bf16* dst = xp + (size_t)n * PPIX * CDIM + ((h + 1) * PW + 1) * CDIM + c;
  for (int w = 0; w < WW; ++w) dst[w * CDIM] = (bf16)src[w];
}

// ---------------- conv3x3 implicit GEMM, 128co x 128px tile, bf16 MFMA
__global__ __launch_bounds__(256) void k_conv(
    const bf16* __restrict__ xp, const bf16* __restrict__ wb,
    float* __restrict__ y)
{
  __shared__ __align__(16) bf16 ldsA[2][4096];
  __shared__ __align__(16) bf16 ldsB[2][4096];
  const int tid = threadIdx.x;
  const int wave = tid >> 6, lane = tid & 63;
  const int pxt = blockIdx.x, cot = blockIdx.y, n = blockIdx.z;

  // staging: each wave issues 2 A-insts + 2 B-insts (1KB each) per K-step.
  // LDS slot (row r, chunk g') holds data chunk g = g' ^ ((r>>1)&3)  (bank-conflict swizzle)
  const int q = lane >> 2;                       // row within 16-row inst
  const int gsw = (lane & 3) ^ ((q >> 1) & 3);   // swizzled source chunk
  const int rA = wave * 32 + q;
  const bf16* aS0 = wb + (size_t)(cot * 128 + rA) * CDIM + gsw * 8;
  const bf16* aS1 = aS0 + 16 * CDIM;
  int pxa = pxt * 128 + rA;       if (pxa > NPX - 1) pxa = NPX - 1;
  int pxb = pxt * 128 + rA + 16;  if (pxb > NPX - 1) pxb = NPX - 1;
  const int ha = pxa / 36, wa = pxa - ha * 36;
  const int hb = pxb / 36, wbv = pxb - hb * 36;
  const bf16* bS0 = xp + (size_t)n * (PPIX * CDIM) + ((ha + 1) * PW + (wa + 1)) * CDIM + gsw * 8;
  const bf16* bS1 = xp + (size_t)n * (PPIX * CDIM) + ((hb + 1) * PW + (wbv + 1)) * CDIM + gsw * 8;

  // fragment-read addressing
  const int fr = lane & 15, fg = lane >> 4;
  const int fsw = (fg ^ ((fr >> 1) & 3)) * 8;
  const int wco = wave >> 1, wpx = wave & 1;
  const int aoff = (wco * 64 + fr) * 32 + fsw;
  const int boff = (wpx * 64 + fr) * 32 + fsw;

  f32x4 acc[4][4];
#pragma unroll
  for (int i = 0; i < 4; ++i)
#pragma unroll
    for (int j = 0; j < 4; ++j) acc[i][j] = f32x4{0.f, 0.f, 0.f, 0.f};

  { // prologue: stage k=0 (tap 0: dh=-1,dw=-1, ci0=0)
    const int xoff = -(PW + 1) * CDIM;
    GLD16(aS0, &ldsA[0][wave * 1024]);
    GLD16(aS1, &ldsA[0][wave * 1024 + 512]);
    GLD16(bS0 + xoff, &ldsB[0][wave * 1024]);
    GLD16(bS1 + xoff, &ldsB[0][wave * 1024 + 512]);
  }

#pragma unroll 2
  for (int k = 0; k < 72; ++k) {
    const int buf = k & 1;
    __syncthreads();   // drains vmcnt: staged buf ready; prior reads of other buf done
    if (k + 1 < 72) {
      const int kn = k + 1;
      const int tap = kn >> 3, ci0 = (kn & 7) << 5;
      const int dh = tap / 3 - 1, dw = tap - (tap / 3) * 3 - 1;
      const int woff = tap * (CDIM * CDIM) + ci0;
      const int xoff = (dh * PW + dw) * CDIM + ci0;
      const int nb = buf ^ 1;
      GLD16(aS0 + woff, &ldsA[nb][wave * 1024]);
      GLD16(aS1 + woff, &ldsA[nb][wave * 1024 + 512]);
      GLD16(bS0 + xoff, &ldsB[nb][wave * 1024]);
      GLD16(bS1 + xoff, &ldsB[nb][wave * 1024 + 512]);
    }
    bf16x8 av[4], bv[4];
#pragma unroll
    for (int i = 0; i < 4; ++i) av[i] = *(const bf16x8*)&ldsA[buf][aoff + i * 512];
#pragma unroll
    for (int j = 0; j < 4; ++j) bv[j] = *(const bf16x8*)&ldsB[buf][boff + j * 512];
#pragma unroll
    for (int i = 0; i < 4; ++i)
#pragma unroll
      for (int j = 0; j < 4; ++j)
        acc[i][j] = __builtin_amdgcn_mfma_f32_16x16x32_bf16(av[i], bv[j], acc[i][j], 0, 0, 0);
  }

  // epilogue: C/D layout col(px)=lane&15, row(co)=(lane>>4)*4+reg
#pragma unroll
  for (int j = 0; j < 4; ++j) {
    const int px = pxt * 128 + wpx * 64 + j * 16 + fr;
    if (px < NPX) {
      float* dst = y + ((size_t)n * NPX + px) * CDIM + cot * 128 + wco * 64 + fg * 4;
#pragma unroll
      for (int i = 0; i < 4; ++i) *(f32x4*)(dst + i * 16) = acc[i][j];
    }
  }
}

// ---------------- per-channel sum/sumsq over rows of a [rows][256] f32 array
__global__ void k_stats(const float* __restrict__ x, float* __restrict__ sum,
                        float* __restrict__ ssq, int rpb) {
  int c = threadIdx.x;
  size_t base = (size_t)blockIdx.x * rpb;
  float s = 0.f, s2 = 0.f;
  for (int i = 0; i < rpb; ++i) {
    float v = x[(base + i) * CDIM + c];
    s += v; s2 += v * v;
  }
  atomicAdd(&sum[c], s);
  atomicAdd(&ssq[c], s2);
}

__global__ void k_finalize(const float* __restrict__ sum, const float* __restrict__ ssq,
                           const float* __restrict__ g, const float* __restrict__ b,
                           float* __restrict__ sc, float* __restrict__ sh, float invn) {
  int c = threadIdx.x;
  float m = sum[c] * invn;
  float v = ssq[c] * invn - m * m;
  float s = g[c] * rsqrtf(v + EPS_BN);
  sc[c] = s;
  sh[c] = b[c] - m * s;
}

// ---------------- y f32 NHWC -> BN+ReLU -> padded NHWC bf16 (interior only)
__global__ void k_normalize(const float* __restrict__ y, const float* __restrict__ sc,
                            const float* __restrict__ sh, bf16* __restrict__ xp) {
  int t = threadIdx.x;
  int n = blockIdx.y;
  int px = blockIdx.x * 4 + (t >> 6);
  int c4 = (t & 63) * 4;
  const float4 v = *(const float4*)(y + ((size_t)n * NPX + px) * CDIM + c4);
  const float4 s = *(const float4*)(sc + c4);
  const float4 b = *(const float4*)(sh + c4);
  int h = px / 36, w = px - h * 36;
  union { bf16 h4[4]; ushort4 u; } pk;
  pk.h4[0] = (bf16)fmaxf(v.x * s.x + b.x, 0.f);
  pk.h4[1] = (bf16)fmaxf(v.y * s.y + b.y, 0.f);
  pk.h4[2] = (bf16)fmaxf(v.z * s.z + b.z, 0.f);
  pk.h4[3] = (bf16)fmaxf(v.w * s.w + b.w, 0.f);
  *(ushort4*)(xp + (size_t)n * PPIX * CDIM + ((h + 1) * PW + (w + 1)) * CDIM + c4) = pk.u;
}

// ---------------- trapezoid cumsum along W (Ux), inline BN+ReLU of y
__global__ void k_p1(const float* __restrict__ y, const float* __restrict__ sc,
                     const float* __restrict__ sh, float* __restrict__ Ux) {
  int c = threadIdx.x, h = blockIdx.x, n = blockIdx.y;
  const float* row = y + ((size_t)n * NPX + h * WW) * CDIM + c;
  float* orow = Ux + ((size_t)n * NPX + h * WW) * CDIM + c;
  float s = sc[c], t = sh[c];
  float prev = fmaxf(row[0] * s + t, 0.f);
  float run = 0.f;
  orow[0] = 0.f;
  for (int w = 1; w < WW; ++w) {
    float cur = fmaxf(row[w * CDIM] * s + t, 0.f);
    run += 0.5f * (prev + cur);
    orow[w * CDIM] = run;
    prev = cur;
  }
}

// ---------------- trapezoid cumsum along H: Uy (of x3) and T (of Ux)
__global__ void k_p2(const float* __restrict__ y, const float* __restrict__ sc,
                     const float* __restrict__ sh, const float* __restrict__ Ux,
                     float* __restrict__ Uy, float* __restrict__ T) {
  int c = threadIdx.x, w = blockIdx.x, n = blockIdx.y;
  size_t base = (size_t)n * NPX * CDIM + (size_t)w * CDIM + c;
  float s = sc[c], t = sh[c];
  float prevF = fmaxf(y[base] * s + t, 0.f);
  float prevU = Ux[base];
  float runF = 0.f, runU = 0.f;
  Uy[base] = 0.f; T[base] = 0.f;
  for (int h = 1; h < HH; ++h) {
    size_t idx = base + (size_t)h * WW * CDIM;
    float f = fmaxf(y[idx] * s + t, 0.f);
    float u = Ux[idx];
    runF += 0.5f * (prevF + f);
    runU += 0.5f * (prevU + u);
    Uy[idx] = runF; T[idx] = runU;
    prevF = f; prevU = u;
  }
}

// ---------------- PrRoI pool: one block per roi, thread=channel; rf[roi][c*16+i*4+j] bf16
__global__ void k_pool(const float* __restrict__ y, const float* __restrict__ sc,
                       const float* __restrict__ sh, const float* __restrict__ Ux,
                       const float* __restrict__ Uy, const float* __restrict__ T,
                       const float* __restrict__ props, bf16* __restrict__ rf) {
  int roi = blockIdx.x, c = threadIdx.x;
  int b = roi >> 4;
  const float* pr = props + (size_t)roi * 4;
  float x1 = pr[0] * 20.f, yy1 = pr[1] * 20.f;
  float x2 = (pr[0] + pr[2]) * 20.f, yy2 = (pr[1] + pr[3]) * 20.f;
  float bw = (x2 - x1) * 0.25f, bh = (yy2 - yy1) * 0.25f;
  float px0a[5], px1a[5], py0a[5], py1a[5];
  int wx[5], hy[5];
#pragma unroll
  for (int j = 0; j < 5; ++j) {
    float xs = fminf(fmaxf(x1 + bw * j, 0.f), 35.f);
    int wi = (int)floorf(xs); wi = wi < 0 ? 0 : (wi > 34 ? 34 : wi);
    float sx = xs - (float)wi;
    float p1 = 0.5f * sx * sx;
    wx[j] = wi; px1a[j] = p1; px0a[j] = sx - p1;
    float ys = fminf(fmaxf(yy1 + bh * j, 0.f), 35.f);
    int hi = (int)floorf(ys); hi = hi < 0 ? 0 : (hi > 34 ? 34 : hi);
    float sy = ys - (float)hi;
    float q1 = 0.5f * sy * sy;
    hy[j] = hi; py1a[j] = q1; py0a[j] = sy - q1;
  }
  float s = sc[c], tt = sh[c];
  const size_t nb = (size_t)b * NPX * CDIM + c;
  float G[5][5];
#pragma unroll
  for (int i = 0; i < 5; ++i) {
    int h0 = hy[i], h1 = h0 + 1;
#pragma unroll
    for (int j = 0; j < 5; ++j) {
      int w0 = wx[j], w1 = w0 + 1;
      size_t i00 = nb + (size_t)(h0 * WW + w0) * CDIM;
      size_t i01 = nb + (size_t)(h0 * WW + w1) * CDIM;
      size_t i10 = nb + (size_t)(h1 * WW + w0) * CDIM;
      size_t i11 = nb + (size_t)(h1 * WW + w1) * CDIM;
      float f00 = fmaxf(y[i00] * s + tt, 0.f);
      float f01 = fmaxf(y[i01] * s + tt, 0.f);
      float f10 = fmaxf(y[i10] * s + tt, 0.f);
      float f11 = fmaxf(y[i11] * s + tt, 0.f);
      G[i][j] = T[i00] + Uy[i00] * px0a[j] + Uy[i01] * px1a[j]
              + py0a[i] * (Ux[i00] + f00 * px0a[j] + f01 * px1a[j])
              + py1a[i] * (Ux[i10] + f10 * px0a[j] + f11 * px1a[j]);
    }
  }
  float area = bw * bh;
  float inv = area > 1e-8f ? 1.f / area : 0.f;
  bf16 outv[16];
#pragma unroll
  for (int i = 0; i < 4; ++i)
#pragma unroll
    for (int j = 0; j < 4; ++j) {
      float d = G[i + 1][j + 1] - G[i][j + 1] - G[i + 1][j] + G[i][j];
      outv[i * 4 + j] = (bf16)(d * inv);
    }
  bf16* dst = rf + (size_t)roi * FCK + c * 16;
  *(us8*)(dst)     = *(us8*)&outv[0];
  *(us8*)(dst + 8) = *(us8*)&outv[8];
}

// ---------------- fc GEMM: fcx[roi][o] += rf[roi][k]*fw[o][k], split-K=8, MFMA
__global__ __launch_bounds__(256) void k_fcgemm(const bf16* __restrict__ rf,
                                                const bf16* __restrict__ fw,
                                                float* __restrict__ fcx) {
  int tid = threadIdx.x, wave = tid >> 6, lane = tid & 63;
  int wo = wave >> 1, wr = wave & 1;
  int rt = blockIdx.x, ot = blockIdx.y, ks = blockIdx.z;
  int fr = lane & 15, fg = lane >> 4;
  const bf16* ap = fw + (size_t)(ot * 64 + wo * 32 + fr) * FCK + ks * 512 + fg * 8;
  const bf16* bp = rf + (size_t)(rt * 64 + wr * 32 + fr) * FCK + ks * 512 + fg * 8;
  f32x4 acc[2][2];
#pragma unroll
  for (int i = 0; i < 2; ++i)
#pragma unroll
    for (int j = 0; j < 2; ++j) acc[i][j] = f32x4{0.f, 0.f, 0.f, 0.f};
#pragma unroll 4
  for (int k = 0; k < 512; k += 32) {
    bf16x8 a0 = *(const bf16x8*)(ap + k);
    bf16x8 a1 = *(const bf16x8*)(ap + 16 * FCK + k);
    bf16x8 b0 = *(const bf16x8*)(bp + k);
    bf16x8 b1 = *(const bf16x8*)(bp + 16 * FCK + k);
    acc[0][0] = __builtin_amdgcn_mfma_f32_16x16x32_bf16(a0, b0, acc[0][0], 0, 0, 0);
    acc[0][1] = __builtin_amdgcn_mfma_f32_16x16x32_bf16(a0, b1, acc[0][1], 0, 0, 0);
    acc[1][0] = __builtin_amdgcn_mfma_f32_16x16x32_bf16(a1, b0, acc[1][0], 0, 0, 0);
    acc[1][1] = __builtin_amdgcn_mfma_f32_16x16x32_bf16(a1, b1, acc[1][1], 0, 0, 0);
  }
#pragma unroll
  for (int i = 0; i < 2; ++i)
#pragma unroll
    for (int j = 0; j < 2; ++j) {
      int o = ot * 64 + wo * 32 + i * 16 + fg * 4;
      int r = rt * 64 + wr * 32 + j * 16 + fr;
      float* dst = fcx + (size_t)r * CDIM + o;
      atomicAdd(&dst[0], acc[i][j][0]);
      atomicAdd(&dst[1], acc[i][j][1]);
      atomicAdd(&dst[2], acc[i][j][2]);
      atomicAdd(&dst[3], acc[i][j][3]);
    }
}

// ---------------- fc BN + ReLU + iou head
__global__ void k_iou(const float* __restrict__ fcx, const float* __restrict__ sc,
                      const float* __restrict__ sh, const float* __restrict__ iw,
                      const float* __restrict__ ib, float* __restrict__ out) {
  __shared__ float red[4];
  int roi = blockIdx.x, t = threadIdx.x;
  float v = fcx[(size_t)roi * CDIM + t];
  v = fmaxf(v * sc[t] + sh[t], 0.f) * iw[t];
#pragma unroll
  for (int o = 32; o > 0; o >>= 1) v += __shfl_down(v, o);
  if ((t & 63) == 0) red[t >> 6] = v;
  __syncthreads();
  if (t == 0) out[roi] = red[0] + red[1] + red[2] + red[3] + ib[0];
}

extern "C" void kernel_launch(void* const* d_in, const int* in_sizes, int n_in,
                              void* d_out, int out_size, void* d_ws, size_t ws_size,
                              hipStream_t stream) {
  (void)in_sizes; (void)n_in; (void)out_size;
  const float* feat  = (const float*)d_in[0];
  const float* props = (const float*)d_in[1];
  const float* convw[3] = {(const float*)d_in[2], (const float*)d_in[6], (const float*)d_in[10]};
  const float* bng[3]   = {(const float*)d_in[4], (const float*)d_in[8], (const float*)d_in[12]};
  const float* bnb[3]   = {(const float*)d_in[5], (const float*)d_in[9], (const float*)d_in[13]};
  const float* fcw  = (const float*)d_in[14];
  const float* fcg  = (const float*)d_in[16];
  const float* fcbb = (const float*)d_in[17];
  const float* iw   = (const float*)d_in[18];
  const float* ib   = (const float*)d_in[19];
  float* out = (float*)d_out;

  char* w = (char*)d_ws;
  size_t off = 0;
  auto take = [&](size_t sz) -> char* { char* p = w + off; off += (sz + 255) & ~(size_t)255; return p; };
  const size_t SZ_XP = (size_t)NIMG * PPIX * CDIM * 2;
  const size_t SZ_Y  = (size_t)NIMG * NPX * CDIM * 4;
  bf16*  xp0 = (bf16*)take(SZ_XP);
  bf16*  xp1 = (bf16*)take(SZ_XP);
  float* y   = (float*)take(SZ_Y);
  float* Ux  = (float*)take(SZ_Y);
  float* Uy  = (float*)take(SZ_Y);
  float* Tt  = (float*)take(SZ_Y);
  bf16*  wb1 = (bf16*)take((size_t)9 * CDIM * CDIM * 2);
  bf16*  wb2 = (bf16*)take((size_t)9 * CDIM * CDIM * 2);
  bf16*  wb3 = (bf16*)take((size_t)9 * CDIM * CDIM * 2);
  bf16*  fwb = (bf16*)take((size_t)CDIM * FCK * 2);
  bf16*  rfb = (bf16*)take((size_t)NROI * FCK * 2);
  float* fcx = (float*)take((size_t)NROI * CDIM * 4);
  float* stat = (float*)take(8 * 256 * 4);
  float* scsh = (float*)take(8 * 256 * 4);
  if (off > ws_size) return;  // workspace too small: fail loudly

  hipMemsetAsync(xp0, 0, SZ_XP, stream);
  hipMemsetAsync(xp1, 0, SZ_XP, stream);
  hipMemsetAsync(stat, 0, 8 * 256 * 4, stream);
  hipMemsetAsync(fcx, 0, (size_t)NROI * CDIM * 4, stream);

  k_wconv<<<dim3(2304), 256, 0, stream>>>(convw[0], wb1);
  k_wconv<<<dim3(2304), 256, 0, stream>>>(convw[1], wb2);
  k_wconv<<<dim3(2304), 256, 0, stream>>>(convw[2], wb3);
  k_cast<<<dim3(4096), 256, 0, stream>>>(fcw, fwb, CDIM * FCK);
  k_convert<<<dim3(HH, NIMG), 256, 0, stream>>>(feat, xp0);

  bf16* wbs[3] = {wb1, wb2, wb3};
  for (int l = 0; l < 3; ++l) {
    bf16* xin = (l == 1) ? xp1 : xp0;           // conv1<-xp0, conv2<-xp1, conv3<-xp0
    k_conv<<<dim3(11, 2, NIMG), 256, 0, stream>>>(xin, wbs[l], y);
    float* su = stat + l * 512; float* sq = su + 256;
    k_stats<<<dim3(256), 256, 0, stream>>>(y, su, sq, 162);
    float* sc = scsh + l * 512; float* sh = sc + 256;
    k_finalize<<<dim3(1), 256, 0, stream>>>(su, sq, bng[l], bnb[l], sc, sh, 1.f / 41472.f);
    if (l < 2) {
      bf16* xo = (l == 0) ? xp1 : xp0;
      k_normalize<<<dim3(NPX / 4, NIMG), 256, 0, stream>>>(y, sc, sh, xo);
    }
  }
  float* sc3 = scsh + 2 * 512; float* sh3 = sc3 + 256;
  k_p1<<<dim3(HH, NIMG), 256, 0, stream>>>(y, sc3, sh3, Ux);
  k_p2<<<dim3(WW, NIMG), 256, 0, stream>>>(y, sc3, sh3, Ux, Uy, Tt);
  k_pool<<<dim3(NROI), 256, 0, stream>>>(y, sc3, sh3, Ux, Uy, Tt, props, rfb);
  k_fcgemm<<<dim3(8, 4, 8), 256, 0, stream>>>(rfb, fwb, fcx);
  float* fsu = stat + 3 * 512; float* fsq = fsu + 256;
  k_stats<<<dim3(256), 256, 0, stream>>>(fcx, fsu, fsq, 2);
  float* fsc = scsh + 3 * 512; float* fsh = fsc + 256;
  k_finalize<<<dim3(1), 256, 0, stream>>>(fsu, fsq, fcg, fcbb, fsc, fsh, 1.f / 512.f);
  k_iou<<<dim3(NROI), 256, 0, stream>>>(fcx, fsc, fsh, iw, ib, out);
}